// Round 3
// baseline (79.052 us; speedup 1.0000x reference)
//
#include <hip/hip_runtime.h>
#include <hip/hip_bf16.h>

#define BN 512   // batch
#define DD 512   // feature dim
#define LL 24    // label dim

#define ST 32    // k1 supertile (rows and cols)
#define KH 256   // k1 K-half staged per LDS pass

typedef __attribute__((ext_vector_type(8))) short short8;  // 8 bf16 = 4 VGPR
typedef __attribute__((ext_vector_type(4))) float f32x4;

// ws layout (float words):
//   [0,512)              masks (u32)
//   [512, 512+262144)    Dm (f32, 512x512)
//   [262656 + {0,1,2}]   accum: sum(f32), cnt(u32), done(u32)

__device__ __forceinline__ float dist_val(float d2, bool diag) {
    d2 = fmaxf(d2, 0.0f);
    float d = sqrtf(d2);
    return diag ? 0.0f : d;
}

__device__ __forceinline__ unsigned pk_bf16(float lo, float hi) {
    __hip_bfloat162 p = __float22bfloat162_rn(make_float2(lo, hi));
    unsigned u;
    __builtin_memcpy(&u, &p, 4);     // type-pun; bit_cast rejects non-trivial ctor
    return u;
}

// pack 8 f32 -> bf16 fragment via v_cvt_pk_bf16_f32, accumulate sum of squares
__device__ __forceinline__ short8 pack8_pk(float4 x, float4 y, float& nrm) {
    nrm = fmaf(x.x, x.x, nrm); nrm = fmaf(x.y, x.y, nrm);
    nrm = fmaf(x.z, x.z, nrm); nrm = fmaf(x.w, x.w, nrm);
    nrm = fmaf(y.x, y.x, nrm); nrm = fmaf(y.y, y.y, nrm);
    nrm = fmaf(y.z, y.z, nrm); nrm = fmaf(y.w, y.w, nrm);
    union { uint4 u; short8 s; } cv;
    cv.u.x = pk_bf16(x.x, x.y);
    cv.u.y = pk_bf16(x.z, x.w);
    cv.u.z = pk_bf16(y.x, y.y);
    cv.u.w = pk_bf16(y.z, y.w);
    return cv.s;
}

// ---------- kernel 1: LDS-staged bf16 MFMA dist, 32x32 supertile / 4 waves ---
// 256 blocks x 256 threads. Per block: stage A rows [ib,ib+32) and B rows
// [jb,jb+32) into LDS in two K-halves via bulk global_load_lds (latency paid
// once per half, all loads in flight), then MFMA from LDS. LDS rows are
// XOR-swizzled (byte ^= (row&7)<<4) on BOTH sides (pre-swizzled global source,
// swizzled ds_read) to break the 16-way row-stride bank conflict.
// Wave w -> 16x16 tile (wi=w>>1, wj=w&1). MFMA frag map (verified):
//   A/B: row = lane&15, k = q*8+[0,8) with q=lane>>4;  C: col=lane&15, row=q*4+p.
__global__ __launch_bounds__(256, 1) void dist_fused_kernel(
    const float* __restrict__ S, const int* __restrict__ labels,
    unsigned* __restrict__ masks, float* __restrict__ Dm, float* __restrict__ accum)
{
    __shared__ float As[ST * KH];   // 32 KB, swizzled
    __shared__ float Bs[ST * KH];   // 32 KB, swizzled

    const int t    = threadIdx.x;
    const int lane = t & 63;
    const int w    = t >> 6;            // wave 0..3
    const int wi   = w >> 1, wj = w & 1;
    const int ib   = blockIdx.y * ST;
    const int jb   = blockIdx.x * ST;

    // ---- masks (y==0 blocks, 32 rows each) + accum/ticket zero (block 0,0) --
    if (blockIdx.y == 0 && t < ST) {
        const int row = blockIdx.x * ST + t;
        const int4* lab4 = (const int4*)(labels + (size_t)row * LL);
        unsigned m = 0;
#pragma unroll
        for (int v = 0; v < 6; v++) {       // 24 ints = 6 x int4 (96B, 16B aligned)
            int4 x = lab4[v];
            m |= (x.x ? 1u : 0u) << (4 * v)
               | (x.y ? 1u : 0u) << (4 * v + 1)
               | (x.z ? 1u : 0u) << (4 * v + 2)
               | (x.w ? 1u : 0u) << (4 * v + 3);
        }
        masks[row] = m;
    }
    if (blockIdx.x == 0 && blockIdx.y == 0 && t == 0) {
        accum[0] = 0.0f;
        ((unsigned*)accum)[1] = 0u;
        ((unsigned*)accum)[2] = 0u;        // done-ticket for k2 finalize
    }

    const int r     = lane & 15;           // frag row (A.m / B.n) = C.col
    const int q     = lane >> 4;           // k-quarter 0..3; C row group
    const int a_row = wi * 16 + r;         // local staged A row
    const int b_row = wj * 16 + r;
    const unsigned swzA = (unsigned)((a_row & 7) << 4);
    const unsigned swzB = (unsigned)((b_row & 7) << 4);

    f32x4 acc = {0.f, 0.f, 0.f, 0.f};
    float nA = 0.f, nB = 0.f;

    for (int h = 0; h < 2; h++) {
        __syncthreads();                   // h=1: LDS reuse fence (h=0 harmless)
        // stage this K-half: per wave 8 A-chunks + 8 B-chunks of 1024 B
#pragma unroll
        for (int c = 0; c < 8; c++) {
            const unsigned g   = ((unsigned)(c * 4 + w) * 64u + (unsigned)lane) * 16u; // byte in 32KB region
            const unsigned row = g >> 10;          // local row (1024 B rows)
            const unsigned x   = g & 1023u;        // byte within row
            const unsigned sx  = x ^ ((row & 7u) << 4);   // inverse-swizzled source
            const float* srcA = S + (size_t)(ib + row) * DD + h * KH + (sx >> 2);
            const float* srcB = S + (size_t)(jb + row) * DD + h * KH + (sx >> 2);
            __builtin_amdgcn_global_load_lds((const unsigned int*)srcA,
                                             (unsigned int*)&As[g >> 2], 16, 0, 0);
            __builtin_amdgcn_global_load_lds((const unsigned int*)srcB,
                                             (unsigned int*)&Bs[g >> 2], 16, 0, 0);
        }
        __syncthreads();                   // drains vmcnt before any ds_read

#pragma unroll
        for (int k0 = 0; k0 < KH; k0 += 32) {
            const unsigned kb4 = (unsigned)((k0 + q * 8) * 4);   // byte k-offset
            const float4 axv = *(const float4*)&As[(a_row * 1024u + ((kb4      ) ^ swzA)) >> 2];
            const float4 ayv = *(const float4*)&As[(a_row * 1024u + ((kb4 + 16u) ^ swzA)) >> 2];
            const float4 bxv = *(const float4*)&Bs[(b_row * 1024u + ((kb4      ) ^ swzB)) >> 2];
            const float4 byv = *(const float4*)&Bs[(b_row * 1024u + ((kb4 + 16u) ^ swzB)) >> 2];
            short8 af = pack8_pk(axv, ayv, nA);
            short8 bf = pack8_pk(bxv, byv, nB);
            acc = __builtin_amdgcn_mfma_f32_16x16x32_bf16(af, bf, acc, 0, 0, 0);
        }
    }

    // norms: row r covered by lanes {r, r+16, r+32, r+48} (disjoint k quarters)
    nA += __shfl_xor(nA, 16); nA += __shfl_xor(nA, 32);
    nB += __shfl_xor(nB, 16); nB += __shfl_xor(nB, 32);

    const int jc = jb + wj * 16 + r;
    const float nj = nB;
#pragma unroll
    for (int p = 0; p < 4; p++) {
        const int ir = ib + wi * 16 + q * 4 + p;
        const float ni = __shfl(nA, q * 4 + p);  // lane (q*4+p) holds row wi*16+q*4+p
        Dm[(size_t)ir * BN + jc] = dist_val(ni + nj - 2.f * acc[p], ir == jc);
    }
}

// ---------------- kernel 2: negative-sparse triplet + fused finalize ---------
// 512 blocks x 1 wave, 1 row each. 512 masks live as m[8] per lane; ballot
// gives the positive set per 64-chunk. Rows with no negatives (~60%, since
// P(neg pair) = (3/4)^24 ~ 0.001) exit before touching the distance row.
// Last-done block (ticket) finalizes. (Structure verified round 2, absmax=0.)
#define K2_BLOCKS 512
#define K2_ROWS   (BN / K2_BLOCKS)   // 1

__global__ __launch_bounds__(64) void triplet_kernel(
    const float* __restrict__ Dm, const unsigned* __restrict__ masks,
    float* __restrict__ accum, float* __restrict__ out)
{
    const int lane = threadIdx.x;

    unsigned m[8];
#pragma unroll
    for (int c = 0; c < 8; c++) m[c] = masks[c * 64 + lane];

    float bsum = 0.f; unsigned bcnt = 0;

    for (int rr = 0; rr < K2_ROWS; rr++) {
        const int i = blockIdx.x * K2_ROWS + rr;
        const unsigned mi = masks[i];          // uniform -> scalar load (L2-hot)

        unsigned long long pb[8];
        unsigned long long anyneg = 0ull;
#pragma unroll
        for (int c = 0; c < 8; c++) {
            pb[c] = __ballot((mi & m[c]) != 0u);
            anyneg |= ~pb[c];
        }
        if (anyneg == 0ull) continue;          // wave-uniform: row contributes nothing

        const float* drow = Dm + (size_t)i * BN;
        float dv[8];
#pragma unroll
        for (int c = 0; c < 8; c++) dv[c] = drow[c * 64 + lane];

#pragma unroll
        for (int c = 0; c < 8; c++) {
            unsigned long long nb = ~pb[c];
            while (nb) {                       // wave-uniform, ~0.5 iters/row avg
                const int k = __ffsll(nb) - 1;
                nb &= nb - 1;
                const float dk = __shfl(dv[c], k);
#pragma unroll
                for (int c2 = 0; c2 < 8; c2++) {
                    if ((pb[c2] >> lane) & 1ull) {   // this lane's j is a positive
                        const float v = dv[c2] - dk;
                        bsum += fmaxf(v, 0.0f);
                        bcnt += (v > 1e-16f) ? 1u : 0u;
                    }
                }
            }
        }
    }

    // wave reduce
#pragma unroll
    for (int off = 32; off > 0; off >>= 1) {
        bsum += __shfl_down(bsum, off);
        bcnt += __shfl_down(bcnt, off);
    }
    if (lane == 0 && (bsum != 0.f || bcnt != 0u)) {
        atomicAdd(&accum[0], bsum);
        atomicAdd(&((unsigned*)accum)[1], bcnt);
    }

    // last-block-done finalize (release fence -> ticket -> acquire fence)
    __threadfence();
    if (lane == 0) {
        const unsigned tk = atomicAdd(&((unsigned*)accum)[2], 1u);
        if (tk == (unsigned)(K2_BLOCKS - 1)) {
            __threadfence();
            const float    s = atomicAdd(&accum[0], 0.0f);            // coherent read
            const unsigned c = atomicAdd(&((unsigned*)accum)[1], 0u); // coherent read
            out[0] = s / ((float)c + 1e-16f);
        }
    }
}

extern "C" void kernel_launch(void* const* d_in, const int* in_sizes, int n_in,
                              void* d_out, int out_size, void* d_ws, size_t ws_size,
                              hipStream_t stream) {
    const float* src    = (const float*)d_in[0];
    const int*   labels = (const int*)d_in[1];
    float* ws = (float*)d_ws;
    unsigned* masks = (unsigned*)ws;
    float*    Dm    = ws + BN;
    float*    accum = ws + BN + (size_t)BN * BN;

    hipLaunchKernelGGL(dist_fused_kernel, dim3(16, 16),    dim3(256), 0, stream,
                       src, labels, masks, Dm, accum);
    hipLaunchKernelGGL(triplet_kernel,    dim3(K2_BLOCKS), dim3(64),  0, stream,
                       Dm, masks, accum, (float*)d_out);
}